// Round 3
// baseline (3380.410 us; speedup 1.0000x reference)
//
#include <hip/hip_runtime.h>

typedef __attribute__((ext_vector_type(4))) float floatx4;
typedef __attribute__((ext_vector_type(8))) _Float16 half8;

// ---------- fp16 helpers (RNE via _Float16 convert) ----------
union H2 { unsigned int u; _Float16 h[2]; };

__device__ __forceinline__ float hs2f(unsigned short u) {
    union { unsigned short u; _Float16 h; } c; c.u = u; return (float)c.h;
}
__device__ __forceinline__ unsigned short f2hs(float f) {
    union { unsigned short u; _Float16 h; } c; c.h = (_Float16)f; return c.u;
}
__device__ __forceinline__ unsigned int pack2h(float a, float b) {
    H2 c; c.h[0] = (_Float16)a; c.h[1] = (_Float16)b; return c.u;
}

// ---------- async global->LDS, 16B per lane ----------
// LDS dest is wave-uniform base + lane*16B. Every staging target below is
// arranged so a wave's lanes write offsets tid*16B within a contiguous panel.
__device__ __forceinline__ void load_lds16(const unsigned short* g, unsigned short* l) {
    __builtin_amdgcn_global_load_lds(
        (__attribute__((address_space(1))) void*)(g),
        (__attribute__((address_space(3))) void*)(l), 16, 0, 0);
}

// ---------- CSR build ----------
__global__ void k_hist(const int* __restrict__ dst, const int* __restrict__ et,
                       int* __restrict__ cnt4, int E) {
    int i = blockIdx.x * 256 + threadIdx.x;
    if (i < E) {
        atomicAdd(&cnt4[dst[i] * 4 + et[i]], 1);
    }
}

__global__ void k_scan_blk(const int* __restrict__ cnt4, int* __restrict__ row_ptr,
                           int* __restrict__ bsum, int N) {
    __shared__ int sm[256];
    int b = blockIdx.x, t = threadIdx.x, i = b * 256 + t;
    int v = 0;
    if (i < N) {
        const int4 q = ((const int4*)cnt4)[i];
        v = q.x + q.y + q.z + q.w;
    }
    sm[t] = v;
    __syncthreads();
    for (int off = 1; off < 256; off <<= 1) {
        int x = (t >= off) ? sm[t - off] : 0;
        __syncthreads();
        sm[t] += x;
        __syncthreads();
    }
    if (i < N) row_ptr[i] = sm[t] - v;
    if (t == 255) bsum[b] = sm[255];
}

__global__ void k_scan_top(int* __restrict__ bsum, int* __restrict__ boff,
                           int* __restrict__ row_ptr, int nblocks, int N) {
    __shared__ int sm[256];
    int t = threadIdx.x;
    int v = (t < nblocks) ? bsum[t] : 0;
    sm[t] = v;
    __syncthreads();
    for (int off = 1; off < 256; off <<= 1) {
        int x = (t >= off) ? sm[t - off] : 0;
        __syncthreads();
        sm[t] += x;
        __syncthreads();
    }
    if (t < nblocks) boff[t] = sm[t] - v;
    if (t == 255) row_ptr[N] = sm[255];
}

__global__ void k_scan_add(int* __restrict__ row_ptr, int* __restrict__ cursor,
                           const int* __restrict__ boff, int N) {
    int i = blockIdx.x * 256 + threadIdx.x;
    if (i < N) {
        int r = row_ptr[i] + boff[blockIdx.x];
        row_ptr[i] = r;
        cursor[i]  = r;
    }
}

__global__ void k_scatter(const int* __restrict__ src, const int* __restrict__ dst,
                          const int* __restrict__ et, int* __restrict__ cursor,
                          int* __restrict__ edge_pk, int E) {
    int i = blockIdx.x * 256 + threadIdx.x;
    if (i < E) {
        int p = atomicAdd(&cursor[dst[i]], 1);
        edge_pk[p] = src[i] | (et[i] << 16);   // src < 65536 for N=50000
    }
}

// ---------- init h (fp16) into AH[:,128:256] ----------
__global__ void k_init_h(const float* __restrict__ feat, unsigned short* __restrict__ AH, int N) {
    int i = blockIdx.x * 256 + threadIdx.x;
    if (i < N * 128) {
        int v = i >> 7, d = i & 127;
        AH[(size_t)v * 256 + 128 + d] = f2hs(feat[i]);
    }
}

// ---------- weight prep: single fp16, n-major [Nout][K] ----------
__global__ void k_prep_wcat(const float* __restrict__ W, unsigned short* __restrict__ w) {
    int i = blockIdx.x * 256 + threadIdx.x;   // 4*128*128 = 65536
    if (i < 65536) {
        int t = i >> 14, o = (i >> 7) & 127, d = i & 127;
        w[o * 512 + t * 128 + d] = f2hs(W[i]);
    }
}

// r,z rows: Wrz[256][256], row j = [W_ih[j] | W_hh[j]]
__global__ void k_prep_wrz(const float* __restrict__ Wih, const float* __restrict__ Whh,
                           unsigned short* __restrict__ w) {
    int i = blockIdx.x * 256 + threadIdx.x;   // 256*256
    if (i < 256 * 256) {
        int j = i >> 8, k = i & 255;
        float v = (k < 128) ? Wih[j * 128 + k] : Whh[j * 128 + (k - 128)];
        w[i] = f2hs(v);
    }
}

// i_n rows: Win[128][128] = W_ih rows 256..383 ; h_n rows: Whn[128][128] = W_hh rows 256..383
__global__ void k_prep_wnh(const float* __restrict__ Wih, const float* __restrict__ Whh,
                           unsigned short* __restrict__ win, unsigned short* __restrict__ whn) {
    int i = blockIdx.x * 256 + threadIdx.x;   // 128*128
    if (i < 128 * 128) {
        int c = i >> 7, k = i & 127;
        win[i] = f2hs(Wih[(256 + c) * 128 + k]);
        whn[i] = f2hs(Whh[(256 + c) * 128 + k]);
    }
}

// ---------- per-step: aggregate h[src] by (dst, etype): S[v][t*128+d] ----------
// LDS-atomic accumulation: type becomes an ADDRESS (acc[wv][t][2][64]) instead
// of a 4-way select chain; ds_add_f32 is fire-and-forget so there is no FP
// dependency chain in VGPRs and the LDS pipe overlaps the VALU/VMEM pipes.
// [2][64] split puts both per-lane atomics at bank=lane%32 (2-way = free, m136).
// Per-(lane,type) accumulation order = edge order -> numerics identical to the
// register version.
__global__ __launch_bounds__(256) void k_aggregate(
    const int* __restrict__ row_ptr, const int* __restrict__ edge_pk,
    const unsigned short* __restrict__ AH, unsigned short* __restrict__ S, int N)
{
    __shared__ float acc[4][4][2][64];     // [wave][etype][dim-parity][lane] = 8 KB
    const int wv   = threadIdx.x >> 6;
    const int lane = threadIdx.x & 63;
    int v = blockIdx.x * 4 + wv;
    if (v >= N) return;
    v = __builtin_amdgcn_readfirstlane(v);

    // zero this wave's 512-float accumulator (no barrier needed: wave-private)
    float2* az = (float2*)&acc[wv][0][0][0];
#pragma unroll
    for (int r = 0; r < 4; ++r) az[r * 64 + lane] = make_float2(0.f, 0.f);

    const int beg = __builtin_amdgcn_readfirstlane(row_ptr[v]);
    const int end = __builtin_amdgcn_readfirstlane(row_ptr[v + 1]);
    const unsigned short* hbase = AH + 128 + lane * 2;
    float* const abase = &acc[wv][0][0][lane];

    for (int e = beg; e < end; e += 8) {
        int ep[8];
        unsigned int hv[8];
#pragma unroll
        for (int u = 0; u < 8; ++u) {
            int idx = e + u;
            if (idx > end - 1) idx = end - 1;
            ep[u] = edge_pk[idx];
        }
#pragma unroll
        for (int u = 0; u < 8; ++u)
            hv[u] = *(const unsigned int*)(hbase + (size_t)(ep[u] & 0xFFFF) * 256);
#pragma unroll
        for (int u = 0; u < 8; ++u) {
            if (e + u < end) {                       // wave-uniform branch
                H2 c; c.u = hv[u];
                float* p = abase + (ep[u] >> 16) * 128;
                atomicAdd(p,      (float)c.h[0]);    // ds_add_f32, bank=lane%32
                atomicAdd(p + 64, (float)c.h[1]);    // ds_add_f32, bank=lane%32
            }
        }
    }

    // same-wave LDS ops are in-order: reads below see all our ds_add results
    unsigned int* Sp = (unsigned int*)&S[(size_t)v * 512];
#pragma unroll
    for (int t = 0; t < 4; ++t)
        Sp[t * 64 + lane] = pack2h(abase[t * 128], abase[t * 128 + 64]);
}

// ---------- etype GEMM: C[128,128] tile, K=512, BK=64 as 2x32 panels, fp16 ----------
__global__ __launch_bounds__(256) void k_gemm0(
    const unsigned short* __restrict__ A, int M,
    const unsigned short* __restrict__ Bw,
    unsigned short* __restrict__ outAH, const int* __restrict__ cnt4,
    const float* __restrict__ b_et)
{
    __shared__ __align__(16) unsigned short As[2][128 * 32];
    __shared__ __align__(16) unsigned short Bs[2][128 * 32];
    const int tid  = threadIdx.x;
    const int lane = tid & 63;
    const int wv   = tid >> 6;
    const int wm   = (wv & 1) * 64;
    const int wn   = (wv >> 1) * 64;
    const int mBase = blockIdx.x * 128;
    const int srow = tid >> 2;
    const int sseg = (tid & 3) * 8;
    const int Ktot = 512;

    floatx4 acc[4][4];
#pragma unroll
    for (int i = 0; i < 4; ++i)
#pragma unroll
        for (int j = 0; j < 4; ++j) acc[i][j] = (floatx4){0.f, 0.f, 0.f, 0.f};

    int r0 = mBase + srow;      if (r0 >= M) r0 = M - 1;
    int r1 = mBase + srow + 64; if (r1 >= M) r1 = M - 1;

    for (int k0 = 0; k0 < Ktot; k0 += 64) {
        __syncthreads();
#pragma unroll
        for (int sub = 0; sub < 2; ++sub) {
            const int ko = k0 + sub * 32;
            load_lds16(A + (size_t)r0 * 512 + ko + sseg, &As[sub][srow * 32 + sseg]);
            load_lds16(A + (size_t)r1 * 512 + ko + sseg, &As[sub][(srow + 64) * 32 + sseg]);
            const unsigned short* bw = Bw + (size_t)srow * Ktot + ko + sseg;
            load_lds16(bw,                     &Bs[sub][srow * 32 + sseg]);
            load_lds16(bw + (size_t)64 * Ktot, &Bs[sub][(srow + 64) * 32 + sseg]);
        }
        __syncthreads();
        const int kof = (lane >> 4) * 8;
        const int mr  = lane & 15;
#pragma unroll
        for (int p = 0; p < 2; ++p) {
            half8 af[4], bf[4];
#pragma unroll
            for (int i = 0; i < 4; ++i) af[i] = *(const half8*)&As[p][(wm + i * 16 + mr) * 32 + kof];
#pragma unroll
            for (int j = 0; j < 4; ++j) bf[j] = *(const half8*)&Bs[p][(wn + j * 16 + mr) * 32 + kof];
#pragma unroll
            for (int i = 0; i < 4; ++i)
#pragma unroll
                for (int j = 0; j < 4; ++j)
                    acc[i][j] = __builtin_amdgcn_mfma_f32_16x16x32_f16(af[i], bf[j], acc[i][j], 0, 0, 0);
        }
    }

    const int mr4 = (lane >> 4) * 4;
    const int nc  = lane & 15;
#pragma unroll
    for (int i = 0; i < 4; ++i) {
#pragma unroll
        for (int r = 0; r < 4; ++r) {
            int row = mBase + wm + i * 16 + mr4 + r;
            if (row < M) {
                int cx = cnt4[row * 4 + 0], cy = cnt4[row * 4 + 1];
                int cz = cnt4[row * 4 + 2], cw = cnt4[row * 4 + 3];
#pragma unroll
                for (int j = 0; j < 4; ++j) {
                    int col = wn + j * 16 + nc;
                    float val = acc[i][j][r]
                        + (float)cx * b_et[col]       + (float)cy * b_et[128 + col]
                        + (float)cz * b_et[256 + col] + (float)cw * b_et[384 + col];
                    outAH[(size_t)row * 256 + col] = f2hs(val);
                }
            }
        }
    }
}

// ---------- gates GEMM, zero-block-eliminated K-split, fp16, BK=64 as 2x32 panels ----------
// grid (mblocks, 4): y=0,1 -> r,z cols (K=256); y=2 -> i_n (K=128, a-half);
// y=3 -> h_n (K=128, h-half). 1564 blocks keeps CUs saturated (the fused
// single-kernel variant measured 79 us at 8% occupancy -- reverted).
__global__ __launch_bounds__(256) void k_gemm1(
    const unsigned short* __restrict__ A, int M,
    const unsigned short* __restrict__ Wrz,
    const unsigned short* __restrict__ Win, const unsigned short* __restrict__ Whn,
    _Float16* __restrict__ G)
{
    __shared__ __align__(16) unsigned short As[2][128 * 32];
    __shared__ __align__(16) unsigned short Bs[2][128 * 32];
    const int tid  = threadIdx.x;
    const int lane = tid & 63;
    const int wv   = tid >> 6;
    const int wm   = (wv & 1) * 64;
    const int wn   = (wv >> 1) * 64;
    const int mBase = blockIdx.x * 128;
    const int y    = blockIdx.y;
    const int srow = tid >> 2;
    const int sseg = (tid & 3) * 8;

    const unsigned short* Bw;
    int Ktot, aOff, colBase;
    if (y < 2)      { Bw = Wrz + (size_t)y * 128 * 256; Ktot = 256; aOff = 0;   colBase = y * 128; }
    else if (y == 2){ Bw = Win; Ktot = 128; aOff = 0;   colBase = 256; }
    else            { Bw = Whn; Ktot = 128; aOff = 128; colBase = 384; }

    floatx4 acc[4][4];
#pragma unroll
    for (int i = 0; i < 4; ++i)
#pragma unroll
        for (int j = 0; j < 4; ++j) acc[i][j] = (floatx4){0.f, 0.f, 0.f, 0.f};

    int r0 = mBase + srow;      if (r0 >= M) r0 = M - 1;
    int r1 = mBase + srow + 64; if (r1 >= M) r1 = M - 1;

    for (int k0 = 0; k0 < Ktot; k0 += 64) {
        __syncthreads();
#pragma unroll
        for (int sub = 0; sub < 2; ++sub) {
            const int ko = k0 + sub * 32;
            load_lds16(A + (size_t)r0 * 256 + aOff + ko + sseg, &As[sub][srow * 32 + sseg]);
            load_lds16(A + (size_t)r1 * 256 + aOff + ko + sseg, &As[sub][(srow + 64) * 32 + sseg]);
            const unsigned short* bw = Bw + (size_t)srow * Ktot + ko + sseg;
            load_lds16(bw,                     &Bs[sub][srow * 32 + sseg]);
            load_lds16(bw + (size_t)64 * Ktot, &Bs[sub][(srow + 64) * 32 + sseg]);
        }
        __syncthreads();
        const int kof = (lane >> 4) * 8;
        const int mr  = lane & 15;
#pragma unroll
        for (int p = 0; p < 2; ++p) {
            half8 af[4], bf[4];
#pragma unroll
            for (int i = 0; i < 4; ++i) af[i] = *(const half8*)&As[p][(wm + i * 16 + mr) * 32 + kof];
#pragma unroll
            for (int j = 0; j < 4; ++j) bf[j] = *(const half8*)&Bs[p][(wn + j * 16 + mr) * 32 + kof];
#pragma unroll
            for (int i = 0; i < 4; ++i)
#pragma unroll
                for (int j = 0; j < 4; ++j)
                    acc[i][j] = __builtin_amdgcn_mfma_f32_16x16x32_f16(af[i], bf[j], acc[i][j], 0, 0, 0);
        }
    }

    const int mr4 = (lane >> 4) * 4;
    const int nc  = lane & 15;
#pragma unroll
    for (int i = 0; i < 4; ++i) {
#pragma unroll
        for (int r = 0; r < 4; ++r) {
            int row = mBase + wm + i * 16 + mr4 + r;
            if (row < M) {
#pragma unroll
                for (int j = 0; j < 4; ++j) {
                    int col = colBase + wn + j * 16 + nc;
                    G[(size_t)row * 512 + col] = (_Float16)acc[i][j][r];
                }
            }
        }
    }
}

// ---------- GRU elementwise (fp16 G, 2 dims/thread) ----------
__global__ void k_gru(const _Float16* __restrict__ G, unsigned short* __restrict__ AH,
                      const float* __restrict__ b_ih, const float* __restrict__ b_hh, int N) {
    int i = blockIdx.x * 256 + threadIdx.x;
    if (i >= N * 64) return;
    int v = i >> 6, j = i & 63;          // pair index (2 dims)
    const unsigned int* g32 = (const unsigned int*)(G + (size_t)v * 512);
    H2 pr, pz, pn, ph;
    pr.u = g32[j];
    pz.u = g32[64 + j];
    pn.u = g32[128 + j];
    ph.u = g32[192 + j];
    H2 hv; hv.u = *(const unsigned int*)&AH[(size_t)v * 256 + 128 + j * 2];
    float outs[2];
#pragma unroll
    for (int q = 0; q < 2; ++q) {
        int d = j * 2 + q;
        float pre_r = (float)pr.h[q] + b_ih[d]       + b_hh[d];
        float pre_z = (float)pz.h[q] + b_ih[128 + d] + b_hh[128 + d];
        float i_n   = (float)pn.h[q] + b_ih[256 + d];
        float h_n   = (float)ph.h[q] + b_hh[256 + d];
        float r = 1.f / (1.f + __expf(-pre_r));
        float z = 1.f / (1.f + __expf(-pre_z));
        float n = tanhf(i_n + r * h_n);
        float h = (float)hv.h[q];
        outs[q] = (1.f - z) * n + z * h;
    }
    *(unsigned int*)&AH[(size_t)v * 256 + 128 + j * 2] = pack2h(outs[0], outs[1]);
}

// ---------- readout stage 1: per-node classifier dot (no atomics) ----------
__global__ void k_dotv(const unsigned short* __restrict__ AH, const float* __restrict__ cls_w,
                       float* __restrict__ dotv, int N) {
    int v = blockIdx.x * 4 + (threadIdx.x >> 6);
    int lane = threadIdx.x & 63;
    if (v >= N) return;
    H2 c; c.u = *(const unsigned int*)&AH[(size_t)v * 256 + 128 + lane * 2];
    float x = (float)c.h[0] * cls_w[lane * 2]
            + (float)c.h[1] * cls_w[lane * 2 + 1];
#pragma unroll
    for (int off = 32; off > 0; off >>= 1) x += __shfl_down(x, off);
    if (lane == 0) dotv[v] = x;
}

// ---------- readout stage 2: per-graph sum over sorted gids + sigmoid ----------
__global__ void k_gsum(const float* __restrict__ dotv, const int* __restrict__ gids,
                       const float* __restrict__ cls_b, float* __restrict__ out, int N) {
    int g = blockIdx.x;
    int t = threadIdx.x;   // 256
    int lo = 0, hi = N;
    while (lo < hi) { int m = (lo + hi) >> 1; if (gids[m] < g) lo = m + 1; else hi = m; }
    int s = lo;
    lo = 0; hi = N;
    while (lo < hi) { int m = (lo + hi) >> 1; if (gids[m] < g + 1) lo = m + 1; else hi = m; }
    int e = lo;
    float acc = 0.f;
    for (int v = s + t; v < e; v += 256) acc += dotv[v];
    __shared__ float red[256];
    red[t] = acc;
    __syncthreads();
    for (int off = 128; off > 0; off >>= 1) {
        if (t < off) red[t] += red[t + off];
        __syncthreads();
    }
    if (t == 0) out[g] = 1.f / (1.f + expf(-(red[0] + cls_b[0])));
}

// ---------- host ----------
extern "C" void kernel_launch(void* const* d_in, const int* in_sizes, int n_in,
                              void* d_out, int out_size, void* d_ws, size_t ws_size,
                              hipStream_t stream) {
    const float* features = (const float*)d_in[0];
    const int*   src      = (const int*)d_in[1];
    const int*   dst      = (const int*)d_in[2];
    const int*   etype    = (const int*)d_in[3];
    const int*   gids     = (const int*)d_in[4];
    const float* W_etype  = (const float*)d_in[5];
    const float* b_etype  = (const float*)d_in[6];
    const float* W_ih     = (const float*)d_in[7];
    const float* W_hh     = (const float*)d_in[8];
    const float* b_ih     = (const float*)d_in[9];
    const float* b_hh     = (const float*)d_in[10];
    const float* cls_w    = (const float*)d_in[11];
    const float* cls_b    = (const float*)d_in[12];
    const int N = in_sizes[0] / 128;
    const int E = in_sizes[1];
    float* out = (float*)d_out;

    char* ws = (char*)d_ws;
    size_t off = 0;
    auto alloc = [&](size_t bytes) -> void* {
        off = (off + 255) & ~(size_t)255;
        void* p = ws + off;
        off += bytes;
        return p;
    };
    unsigned short* AH  = (unsigned short*)alloc((size_t)N * 256 * 2); // [a | h] fp16
    unsigned short* S   = (unsigned short*)alloc((size_t)N * 512 * 2); // fp16
    _Float16*       G   = (_Float16*)alloc((size_t)N * 512 * 2);       // fp16 gates
    unsigned short* Wc  = (unsigned short*)alloc(128 * 512 * 2);
    unsigned short* Wrz = (unsigned short*)alloc(256 * 256 * 2);
    unsigned short* Win = (unsigned short*)alloc(128 * 128 * 2);
    unsigned short* Whn = (unsigned short*)alloc(128 * 128 * 2);
    int* row_ptr = (int*)alloc((size_t)(N + 1) * 4);
    int* cursor  = (int*)alloc((size_t)N * 4);
    int* cnt4    = (int*)alloc((size_t)N * 16);
    int* edge_pk = (int*)alloc((size_t)E * 4);
    float* dotv  = (float*)alloc((size_t)N * 4);
    int* bsum    = (int*)alloc(256 * 4);
    int* boff    = (int*)alloc(256 * 4);
    (void)ws_size; (void)n_in;

    const int nscan = (N + 255) / 256;   // must be <= 256
    hipMemsetAsync(cnt4, 0, (size_t)N * 16, stream);
    k_hist<<<(E + 255) / 256, 256, 0, stream>>>(dst, etype, cnt4, E);
    k_scan_blk<<<nscan, 256, 0, stream>>>(cnt4, row_ptr, bsum, N);
    k_scan_top<<<1, 256, 0, stream>>>(bsum, boff, row_ptr, nscan, N);
    k_scan_add<<<nscan, 256, 0, stream>>>(row_ptr, cursor, boff, N);
    k_scatter<<<(E + 255) / 256, 256, 0, stream>>>(src, dst, etype, cursor, edge_pk, E);
    k_init_h<<<(N * 128 + 255) / 256, 256, 0, stream>>>(features, AH, N);
    k_prep_wcat<<<65536 / 256, 256, 0, stream>>>(W_etype, Wc);
    k_prep_wrz<<<(256 * 256) / 256, 256, 0, stream>>>(W_ih, W_hh, Wrz);
    k_prep_wnh<<<(128 * 128) / 256, 256, 0, stream>>>(W_ih, W_hh, Win, Whn);

    const int mblocks128 = (N + 127) / 128;
    for (int s = 0; s < 8; ++s) {
        k_aggregate<<<(N + 3) / 4, 256, 0, stream>>>(row_ptr, edge_pk, AH, S, N);
        k_gemm0<<<mblocks128, 256, 0, stream>>>(S, N, Wc, AH, cnt4, b_etype);
        dim3 g2(mblocks128, 4);
        k_gemm1<<<g2, 256, 0, stream>>>(AH, N, Wrz, Win, Whn, G);
        k_gru<<<(N * 64 + 255) / 256, 256, 0, stream>>>(G, AH, b_ih, b_hh, N);
    }
    k_dotv<<<(N + 3) / 4, 256, 0, stream>>>(AH, cls_w, dotv, N);
    k_gsum<<<out_size, 256, 0, stream>>>(dotv, gids, cls_b, out, N);
}

// Round 4
// 954.159 us; speedup vs baseline: 3.5428x; 3.5428x over previous
//
#include <hip/hip_runtime.h>

typedef __attribute__((ext_vector_type(4))) float floatx4;
typedef __attribute__((ext_vector_type(8))) _Float16 half8;

// ---------- fp16 helpers (RNE via _Float16 convert) ----------
union H2 { unsigned int u; _Float16 h[2]; };

__device__ __forceinline__ float hs2f(unsigned short u) {
    union { unsigned short u; _Float16 h; } c; c.u = u; return (float)c.h;
}
__device__ __forceinline__ unsigned short f2hs(float f) {
    union { unsigned short u; _Float16 h; } c; c.h = (_Float16)f; return c.u;
}
__device__ __forceinline__ unsigned int pack2h(float a, float b) {
    H2 c; c.h[0] = (_Float16)a; c.h[1] = (_Float16)b; return c.u;
}

// ---------- async global->LDS, 16B per lane ----------
// LDS dest is wave-uniform base + lane*16B. Every staging target below is
// arranged so a wave's lanes write offsets tid*16B within a contiguous panel.
__device__ __forceinline__ void load_lds16(const unsigned short* g, unsigned short* l) {
    __builtin_amdgcn_global_load_lds(
        (__attribute__((address_space(1))) void*)(g),
        (__attribute__((address_space(3))) void*)(l), 16, 0, 0);
}

// ---------- CSR build ----------
__global__ void k_hist(const int* __restrict__ dst, const int* __restrict__ et,
                       int* __restrict__ cnt4, int E) {
    int i = blockIdx.x * 256 + threadIdx.x;
    if (i < E) {
        atomicAdd(&cnt4[dst[i] * 4 + et[i]], 1);
    }
}

__global__ void k_scan_blk(const int* __restrict__ cnt4, int* __restrict__ row_ptr,
                           int* __restrict__ bsum, int N) {
    __shared__ int sm[256];
    int b = blockIdx.x, t = threadIdx.x, i = b * 256 + t;
    int v = 0;
    if (i < N) {
        const int4 q = ((const int4*)cnt4)[i];
        v = q.x + q.y + q.z + q.w;
    }
    sm[t] = v;
    __syncthreads();
    for (int off = 1; off < 256; off <<= 1) {
        int x = (t >= off) ? sm[t - off] : 0;
        __syncthreads();
        sm[t] += x;
        __syncthreads();
    }
    if (i < N) row_ptr[i] = sm[t] - v;
    if (t == 255) bsum[b] = sm[255];
}

__global__ void k_scan_top(int* __restrict__ bsum, int* __restrict__ boff,
                           int* __restrict__ row_ptr, int nblocks, int N) {
    __shared__ int sm[256];
    int t = threadIdx.x;
    int v = (t < nblocks) ? bsum[t] : 0;
    sm[t] = v;
    __syncthreads();
    for (int off = 1; off < 256; off <<= 1) {
        int x = (t >= off) ? sm[t - off] : 0;
        __syncthreads();
        sm[t] += x;
        __syncthreads();
    }
    if (t < nblocks) boff[t] = sm[t] - v;
    if (t == 255) row_ptr[N] = sm[255];
}

// per-(dst,type) segment cursors: cursor4[v][t] = row_ptr[v] + prefix(cnt4[v][0..t-1])
__global__ void k_scan_add(int* __restrict__ row_ptr, int* __restrict__ cursor4,
                           const int* __restrict__ boff, const int* __restrict__ cnt4, int N) {
    int i = blockIdx.x * 256 + threadIdx.x;
    if (i < N) {
        int r = row_ptr[i] + boff[blockIdx.x];
        row_ptr[i] = r;
        const int4 q = ((const int4*)cnt4)[i];
        int4 c;
        c.x = r;
        c.y = r + q.x;
        c.z = r + q.x + q.y;
        c.w = r + q.x + q.y + q.z;
        ((int4*)cursor4)[i] = c;
    }
}

// edges sorted by (dst, etype): within a dst bucket, types form contiguous
// segments -> aggregate resolves type by wave-uniform scalar compare, not a
// per-lane cndmask chain. edge_pk now stores src only.
__global__ void k_scatter(const int* __restrict__ src, const int* __restrict__ dst,
                          const int* __restrict__ et, int* __restrict__ cursor4,
                          int* __restrict__ edge_pk, int E) {
    int i = blockIdx.x * 256 + threadIdx.x;
    if (i < E) {
        int p = atomicAdd(&cursor4[dst[i] * 4 + et[i]], 1);
        edge_pk[p] = src[i];
    }
}

// ---------- init h (fp16) into AH[:,128:256] ----------
__global__ void k_init_h(const float* __restrict__ feat, unsigned short* __restrict__ AH, int N) {
    int i = blockIdx.x * 256 + threadIdx.x;
    if (i < N * 128) {
        int v = i >> 7, d = i & 127;
        AH[(size_t)v * 256 + 128 + d] = f2hs(feat[i]);
    }
}

// ---------- weight prep: single fp16, n-major [Nout][K] ----------
__global__ void k_prep_wcat(const float* __restrict__ W, unsigned short* __restrict__ w) {
    int i = blockIdx.x * 256 + threadIdx.x;   // 4*128*128 = 65536
    if (i < 65536) {
        int t = i >> 14, o = (i >> 7) & 127, d = i & 127;
        w[o * 512 + t * 128 + d] = f2hs(W[i]);
    }
}

// r,z rows: Wrz[256][256], row j = [W_ih[j] | W_hh[j]]
__global__ void k_prep_wrz(const float* __restrict__ Wih, const float* __restrict__ Whh,
                           unsigned short* __restrict__ w) {
    int i = blockIdx.x * 256 + threadIdx.x;   // 256*256
    if (i < 256 * 256) {
        int j = i >> 8, k = i & 255;
        float v = (k < 128) ? Wih[j * 128 + k] : Whh[j * 128 + (k - 128)];
        w[i] = f2hs(v);
    }
}

// i_n rows: Win[128][128] = W_ih rows 256..383 ; h_n rows: Whn[128][128] = W_hh rows 256..383
__global__ void k_prep_wnh(const float* __restrict__ Wih, const float* __restrict__ Whh,
                           unsigned short* __restrict__ win, unsigned short* __restrict__ whn) {
    int i = blockIdx.x * 256 + threadIdx.x;   // 128*128
    if (i < 128 * 128) {
        int c = i >> 7, k = i & 127;
        win[i] = f2hs(Wih[(256 + c) * 128 + k]);
        whn[i] = f2hs(Whh[(256 + c) * 128 + k]);
    }
}

// ---------- per-step: aggregate h[src] by (dst, etype): S[v][t*128+d] ----------
// Register accumulators (LDS-atomic variant measured 347us at 1.5% VALUBusy --
// reverted). Types are contiguous segments within each bucket (sorted scatter),
// so the accumulator pick is a scalar compare on the wave-uniform edge index:
// ~4-5 VALU/edge (2 cvt + 2 fadd) vs ~24 for the old per-lane cndmask chain.
__global__ __launch_bounds__(256) void k_aggregate(
    const int* __restrict__ row_ptr, const int* __restrict__ cnt4,
    const int* __restrict__ edge_pk,
    const unsigned short* __restrict__ AH, unsigned short* __restrict__ S, int N)
{
    int wv = threadIdx.x >> 6;
    int lane = threadIdx.x & 63;
    int v = blockIdx.x * 4 + wv;
    if (v >= N) return;
    const int beg = __builtin_amdgcn_readfirstlane(row_ptr[v]);
    const int end = __builtin_amdgcn_readfirstlane(row_ptr[v + 1]);
    const int4 q = ((const int4*)cnt4)[v];
    const int b1 = beg + __builtin_amdgcn_readfirstlane(q.x);
    const int b2 = b1 + __builtin_amdgcn_readfirstlane(q.y);
    const int b3 = b2 + __builtin_amdgcn_readfirstlane(q.z);

    float a0x = 0, a0y = 0, a1x = 0, a1y = 0, a2x = 0, a2y = 0, a3x = 0, a3y = 0;
    const unsigned short* hbase = AH + 128 + lane * 2;

    for (int e = beg; e < end; e += 8) {
        int sp[8];
        unsigned int hv[8];
#pragma unroll
        for (int u = 0; u < 8; ++u) {
            int idx = e + u;
            if (idx > end - 1) idx = end - 1;
            sp[u] = edge_pk[idx];
        }
#pragma unroll
        for (int u = 0; u < 8; ++u)
            hv[u] = *(const unsigned int*)(hbase + (size_t)sp[u] * 256);
#pragma unroll
        for (int u = 0; u < 8; ++u) {
            const int idx = e + u;              // wave-uniform
            if (idx < end) {
                H2 c; c.u = hv[u];
                float x0 = (float)c.h[0];
                float x1 = (float)c.h[1];
                if (idx < b1)      { a0x += x0; a0y += x1; }
                else if (idx < b2) { a1x += x0; a1y += x1; }
                else if (idx < b3) { a2x += x0; a2y += x1; }
                else               { a3x += x0; a3y += x1; }
            }
        }
    }

    unsigned int* Sp = (unsigned int*)&S[(size_t)v * 512];
    Sp[lane]       = pack2h(a0x, a0y);
    Sp[64 + lane]  = pack2h(a1x, a1y);
    Sp[128 + lane] = pack2h(a2x, a2y);
    Sp[192 + lane] = pack2h(a3x, a3y);
}

// ---------- etype GEMM: C[128,128] tile, K=512, BK=64 as 2x32 panels, fp16 ----------
__global__ __launch_bounds__(256) void k_gemm0(
    const unsigned short* __restrict__ A, int M,
    const unsigned short* __restrict__ Bw,
    unsigned short* __restrict__ outAH, const int* __restrict__ cnt4,
    const float* __restrict__ b_et)
{
    __shared__ __align__(16) unsigned short As[2][128 * 32];
    __shared__ __align__(16) unsigned short Bs[2][128 * 32];
    const int tid  = threadIdx.x;
    const int lane = tid & 63;
    const int wv   = tid >> 6;
    const int wm   = (wv & 1) * 64;
    const int wn   = (wv >> 1) * 64;
    const int mBase = blockIdx.x * 128;
    const int srow = tid >> 2;
    const int sseg = (tid & 3) * 8;
    const int Ktot = 512;

    floatx4 acc[4][4];
#pragma unroll
    for (int i = 0; i < 4; ++i)
#pragma unroll
        for (int j = 0; j < 4; ++j) acc[i][j] = (floatx4){0.f, 0.f, 0.f, 0.f};

    int r0 = mBase + srow;      if (r0 >= M) r0 = M - 1;
    int r1 = mBase + srow + 64; if (r1 >= M) r1 = M - 1;

    for (int k0 = 0; k0 < Ktot; k0 += 64) {
        __syncthreads();
#pragma unroll
        for (int sub = 0; sub < 2; ++sub) {
            const int ko = k0 + sub * 32;
            load_lds16(A + (size_t)r0 * 512 + ko + sseg, &As[sub][srow * 32 + sseg]);
            load_lds16(A + (size_t)r1 * 512 + ko + sseg, &As[sub][(srow + 64) * 32 + sseg]);
            const unsigned short* bw = Bw + (size_t)srow * Ktot + ko + sseg;
            load_lds16(bw,                     &Bs[sub][srow * 32 + sseg]);
            load_lds16(bw + (size_t)64 * Ktot, &Bs[sub][(srow + 64) * 32 + sseg]);
        }
        __syncthreads();
        const int kof = (lane >> 4) * 8;
        const int mr  = lane & 15;
#pragma unroll
        for (int p = 0; p < 2; ++p) {
            half8 af[4], bf[4];
#pragma unroll
            for (int i = 0; i < 4; ++i) af[i] = *(const half8*)&As[p][(wm + i * 16 + mr) * 32 + kof];
#pragma unroll
            for (int j = 0; j < 4; ++j) bf[j] = *(const half8*)&Bs[p][(wn + j * 16 + mr) * 32 + kof];
#pragma unroll
            for (int i = 0; i < 4; ++i)
#pragma unroll
                for (int j = 0; j < 4; ++j)
                    acc[i][j] = __builtin_amdgcn_mfma_f32_16x16x32_f16(af[i], bf[j], acc[i][j], 0, 0, 0);
        }
    }

    const int mr4 = (lane >> 4) * 4;
    const int nc  = lane & 15;
#pragma unroll
    for (int i = 0; i < 4; ++i) {
#pragma unroll
        for (int r = 0; r < 4; ++r) {
            int row = mBase + wm + i * 16 + mr4 + r;
            if (row < M) {
                int cx = cnt4[row * 4 + 0], cy = cnt4[row * 4 + 1];
                int cz = cnt4[row * 4 + 2], cw = cnt4[row * 4 + 3];
#pragma unroll
                for (int j = 0; j < 4; ++j) {
                    int col = wn + j * 16 + nc;
                    float val = acc[i][j][r]
                        + (float)cx * b_et[col]       + (float)cy * b_et[128 + col]
                        + (float)cz * b_et[256 + col] + (float)cw * b_et[384 + col];
                    outAH[(size_t)row * 256 + col] = f2hs(val);
                }
            }
        }
    }
}

// ---------- gates GEMM, zero-block-eliminated K-split, fp16, BK=64 as 2x32 panels ----------
// grid (mblocks, 4): y=0,1 -> r,z cols (K=256); y=2 -> i_n (K=128, a-half);
// y=3 -> h_n (K=128, h-half). 1564 blocks keeps CUs saturated (the fused
// single-kernel variant measured 79 us at 8% occupancy -- reverted).
__global__ __launch_bounds__(256) void k_gemm1(
    const unsigned short* __restrict__ A, int M,
    const unsigned short* __restrict__ Wrz,
    const unsigned short* __restrict__ Win, const unsigned short* __restrict__ Whn,
    _Float16* __restrict__ G)
{
    __shared__ __align__(16) unsigned short As[2][128 * 32];
    __shared__ __align__(16) unsigned short Bs[2][128 * 32];
    const int tid  = threadIdx.x;
    const int lane = tid & 63;
    const int wv   = tid >> 6;
    const int wm   = (wv & 1) * 64;
    const int wn   = (wv >> 1) * 64;
    const int mBase = blockIdx.x * 128;
    const int y    = blockIdx.y;
    const int srow = tid >> 2;
    const int sseg = (tid & 3) * 8;

    const unsigned short* Bw;
    int Ktot, aOff, colBase;
    if (y < 2)      { Bw = Wrz + (size_t)y * 128 * 256; Ktot = 256; aOff = 0;   colBase = y * 128; }
    else if (y == 2){ Bw = Win; Ktot = 128; aOff = 0;   colBase = 256; }
    else            { Bw = Whn; Ktot = 128; aOff = 128; colBase = 384; }

    floatx4 acc[4][4];
#pragma unroll
    for (int i = 0; i < 4; ++i)
#pragma unroll
        for (int j = 0; j < 4; ++j) acc[i][j] = (floatx4){0.f, 0.f, 0.f, 0.f};

    int r0 = mBase + srow;      if (r0 >= M) r0 = M - 1;
    int r1 = mBase + srow + 64; if (r1 >= M) r1 = M - 1;

    for (int k0 = 0; k0 < Ktot; k0 += 64) {
        __syncthreads();
#pragma unroll
        for (int sub = 0; sub < 2; ++sub) {
            const int ko = k0 + sub * 32;
            load_lds16(A + (size_t)r0 * 256 + aOff + ko + sseg, &As[sub][srow * 32 + sseg]);
            load_lds16(A + (size_t)r1 * 256 + aOff + ko + sseg, &As[sub][(srow + 64) * 32 + sseg]);
            const unsigned short* bw = Bw + (size_t)srow * Ktot + ko + sseg;
            load_lds16(bw,                     &Bs[sub][srow * 32 + sseg]);
            load_lds16(bw + (size_t)64 * Ktot, &Bs[sub][(srow + 64) * 32 + sseg]);
        }
        __syncthreads();
        const int kof = (lane >> 4) * 8;
        const int mr  = lane & 15;
#pragma unroll
        for (int p = 0; p < 2; ++p) {
            half8 af[4], bf[4];
#pragma unroll
            for (int i = 0; i < 4; ++i) af[i] = *(const half8*)&As[p][(wm + i * 16 + mr) * 32 + kof];
#pragma unroll
            for (int j = 0; j < 4; ++j) bf[j] = *(const half8*)&Bs[p][(wn + j * 16 + mr) * 32 + kof];
#pragma unroll
            for (int i = 0; i < 4; ++i)
#pragma unroll
                for (int j = 0; j < 4; ++j)
                    acc[i][j] = __builtin_amdgcn_mfma_f32_16x16x32_f16(af[i], bf[j], acc[i][j], 0, 0, 0);
        }
    }

    const int mr4 = (lane >> 4) * 4;
    const int nc  = lane & 15;
#pragma unroll
    for (int i = 0; i < 4; ++i) {
#pragma unroll
        for (int r = 0; r < 4; ++r) {
            int row = mBase + wm + i * 16 + mr4 + r;
            if (row < M) {
#pragma unroll
                for (int j = 0; j < 4; ++j) {
                    int col = colBase + wn + j * 16 + nc;
                    G[(size_t)row * 512 + col] = (_Float16)acc[i][j][r];
                }
            }
        }
    }
}

// ---------- GRU elementwise (fp16 G, 2 dims/thread) ----------
__global__ void k_gru(const _Float16* __restrict__ G, unsigned short* __restrict__ AH,
                      const float* __restrict__ b_ih, const float* __restrict__ b_hh, int N) {
    int i = blockIdx.x * 256 + threadIdx.x;
    if (i >= N * 64) return;
    int v = i >> 6, j = i & 63;          // pair index (2 dims)
    const unsigned int* g32 = (const unsigned int*)(G + (size_t)v * 512);
    H2 pr, pz, pn, ph;
    pr.u = g32[j];
    pz.u = g32[64 + j];
    pn.u = g32[128 + j];
    ph.u = g32[192 + j];
    H2 hv; hv.u = *(const unsigned int*)&AH[(size_t)v * 256 + 128 + j * 2];
    float outs[2];
#pragma unroll
    for (int q = 0; q < 2; ++q) {
        int d = j * 2 + q;
        float pre_r = (float)pr.h[q] + b_ih[d]       + b_hh[d];
        float pre_z = (float)pz.h[q] + b_ih[128 + d] + b_hh[128 + d];
        float i_n   = (float)pn.h[q] + b_ih[256 + d];
        float h_n   = (float)ph.h[q] + b_hh[256 + d];
        float r = 1.f / (1.f + __expf(-pre_r));
        float z = 1.f / (1.f + __expf(-pre_z));
        float n = tanhf(i_n + r * h_n);
        float h = (float)hv.h[q];
        outs[q] = (1.f - z) * n + z * h;
    }
    *(unsigned int*)&AH[(size_t)v * 256 + 128 + j * 2] = pack2h(outs[0], outs[1]);
}

// ---------- readout stage 1: per-node classifier dot (no atomics) ----------
__global__ void k_dotv(const unsigned short* __restrict__ AH, const float* __restrict__ cls_w,
                       float* __restrict__ dotv, int N) {
    int v = blockIdx.x * 4 + (threadIdx.x >> 6);
    int lane = threadIdx.x & 63;
    if (v >= N) return;
    H2 c; c.u = *(const unsigned int*)&AH[(size_t)v * 256 + 128 + lane * 2];
    float x = (float)c.h[0] * cls_w[lane * 2]
            + (float)c.h[1] * cls_w[lane * 2 + 1];
#pragma unroll
    for (int off = 32; off > 0; off >>= 1) x += __shfl_down(x, off);
    if (lane == 0) dotv[v] = x;
}

// ---------- readout stage 2: per-graph sum over sorted gids + sigmoid ----------
__global__ void k_gsum(const float* __restrict__ dotv, const int* __restrict__ gids,
                       const float* __restrict__ cls_b, float* __restrict__ out, int N) {
    int g = blockIdx.x;
    int t = threadIdx.x;   // 256
    int lo = 0, hi = N;
    while (lo < hi) { int m = (lo + hi) >> 1; if (gids[m] < g) lo = m + 1; else hi = m; }
    int s = lo;
    lo = 0; hi = N;
    while (lo < hi) { int m = (lo + hi) >> 1; if (gids[m] < g + 1) lo = m + 1; else hi = m; }
    int e = lo;
    float acc = 0.f;
    for (int v = s + t; v < e; v += 256) acc += dotv[v];
    __shared__ float red[256];
    red[t] = acc;
    __syncthreads();
    for (int off = 128; off > 0; off >>= 1) {
        if (t < off) red[t] += red[t + off];
        __syncthreads();
    }
    if (t == 0) out[g] = 1.f / (1.f + expf(-(red[0] + cls_b[0])));
}

// ---------- host ----------
extern "C" void kernel_launch(void* const* d_in, const int* in_sizes, int n_in,
                              void* d_out, int out_size, void* d_ws, size_t ws_size,
                              hipStream_t stream) {
    const float* features = (const float*)d_in[0];
    const int*   src      = (const int*)d_in[1];
    const int*   dst      = (const int*)d_in[2];
    const int*   etype    = (const int*)d_in[3];
    const int*   gids     = (const int*)d_in[4];
    const float* W_etype  = (const float*)d_in[5];
    const float* b_etype  = (const float*)d_in[6];
    const float* W_ih     = (const float*)d_in[7];
    const float* W_hh     = (const float*)d_in[8];
    const float* b_ih     = (const float*)d_in[9];
    const float* b_hh     = (const float*)d_in[10];
    const float* cls_w    = (const float*)d_in[11];
    const float* cls_b    = (const float*)d_in[12];
    const int N = in_sizes[0] / 128;
    const int E = in_sizes[1];
    float* out = (float*)d_out;

    char* ws = (char*)d_ws;
    size_t off = 0;
    auto alloc = [&](size_t bytes) -> void* {
        off = (off + 255) & ~(size_t)255;
        void* p = ws + off;
        off += bytes;
        return p;
    };
    unsigned short* AH  = (unsigned short*)alloc((size_t)N * 256 * 2); // [a | h] fp16
    unsigned short* S   = (unsigned short*)alloc((size_t)N * 512 * 2); // fp16
    _Float16*       G   = (_Float16*)alloc((size_t)N * 512 * 2);       // fp16 gates
    unsigned short* Wc  = (unsigned short*)alloc(128 * 512 * 2);
    unsigned short* Wrz = (unsigned short*)alloc(256 * 256 * 2);
    unsigned short* Win = (unsigned short*)alloc(128 * 128 * 2);
    unsigned short* Whn = (unsigned short*)alloc(128 * 128 * 2);
    int* row_ptr = (int*)alloc((size_t)(N + 1) * 4);
    int* cursor4 = (int*)alloc((size_t)N * 16);
    int* cnt4    = (int*)alloc((size_t)N * 16);
    int* edge_pk = (int*)alloc((size_t)E * 4);
    float* dotv  = (float*)alloc((size_t)N * 4);
    int* bsum    = (int*)alloc(256 * 4);
    int* boff    = (int*)alloc(256 * 4);
    (void)ws_size; (void)n_in;

    const int nscan = (N + 255) / 256;   // must be <= 256
    hipMemsetAsync(cnt4, 0, (size_t)N * 16, stream);
    k_hist<<<(E + 255) / 256, 256, 0, stream>>>(dst, etype, cnt4, E);
    k_scan_blk<<<nscan, 256, 0, stream>>>(cnt4, row_ptr, bsum, N);
    k_scan_top<<<1, 256, 0, stream>>>(bsum, boff, row_ptr, nscan, N);
    k_scan_add<<<nscan, 256, 0, stream>>>(row_ptr, cursor4, boff, cnt4, N);
    k_scatter<<<(E + 255) / 256, 256, 0, stream>>>(src, dst, etype, cursor4, edge_pk, E);
    k_init_h<<<(N * 128 + 255) / 256, 256, 0, stream>>>(features, AH, N);
    k_prep_wcat<<<65536 / 256, 256, 0, stream>>>(W_etype, Wc);
    k_prep_wrz<<<(256 * 256) / 256, 256, 0, stream>>>(W_ih, W_hh, Wrz);
    k_prep_wnh<<<(128 * 128) / 256, 256, 0, stream>>>(W_ih, W_hh, Win, Whn);

    const int mblocks128 = (N + 127) / 128;
    for (int s = 0; s < 8; ++s) {
        k_aggregate<<<(N + 3) / 4, 256, 0, stream>>>(row_ptr, cnt4, edge_pk, AH, S, N);
        k_gemm0<<<mblocks128, 256, 0, stream>>>(S, N, Wc, AH, cnt4, b_etype);
        dim3 g2(mblocks128, 4);
        k_gemm1<<<g2, 256, 0, stream>>>(AH, N, Wrz, Win, Whn, G);
        k_gru<<<(N * 64 + 255) / 256, 256, 0, stream>>>(G, AH, b_ih, b_hh, N);
    }
    k_dotv<<<(N + 3) / 4, 256, 0, stream>>>(AH, cls_w, dotv, N);
    k_gsum<<<out_size, 256, 0, stream>>>(dotv, gids, cls_b, out, N);
}